// Round 7
// baseline (115.561 us; speedup 1.0000x reference)
//
#include <hip/hip_runtime.h>

// EncoderBlock, fused single kernel, BN block-local, BARRIER-FREE K-loop:
//   gather(x, idx) -> GEMM slice (M=512 batches x N=32 cols @ K=512) + bias
//   -> BN stats over the block's own 512 rows -> SiLU -> fp32 out.
// Grid: 256 blocks = (o, 32-col slice) x 1024 threads (16 waves, 4/SIMD).
// Key change vs R3/R6: the block's ENTIRE B panel (512k x 32e = 32KB bf16)
// is staged to LDS ONCE up front (one __syncthreads). The K-loop then has
// NO barriers: A is wave-private (direct-to-register, k-contiguous in x,
// depth-2 register prefetch), B is read-only LDS. 16 waves free-run ->
// latency hidden by TLP instead of a lockstep pipeline (kills the 2-phase
// stage+vmcnt+barrier stall that dominated R3/R6).
// No cross-block sync anywhere (rounds 2/4/5: grid-scale sync costs 50-80us).

typedef __attribute__((ext_vector_type(8))) __bf16 bf16x8;
typedef __attribute__((ext_vector_type(4))) float  f32x4;

#define FEAT 8192
#define XROW 8192            // N_IN * D_IN floats per batch row of x
#define LDSB 520             // B panel e-row stride in bf16 (512 + 8 pad)

__global__ __launch_bounds__(1024, 4)
void fused_encoder(const float* __restrict__ x, const float* __restrict__ W,
                   const float* __restrict__ bias, const float* __restrict__ gamma,
                   const float* __restrict__ beta, const int* __restrict__ idxp,
                   float* __restrict__ out)
{
    __shared__ __bf16 Bpan[32 * LDSB];   // 32.5 KiB: full B^T panel [e][k]
    __shared__ float Sred[16][32];
    __shared__ float Qred[16][32];
    __shared__ float sscale[32];
    __shared__ float sshift[32];

    // XCD-aware decode: 4 col-slices of one o share an XCD (shared gathered-A
    // panel stays L2-resident; perf heuristic only).
    const int bid = blockIdx.x;
    const int o   = ((bid >> 5) << 3) | (bid & 7);
    const int es  = (bid >> 3) & 3;
    const int e0  = es * 32;

    const int tid  = threadIdx.x;
    const int wave = tid >> 6;          // 0..15 -> rows wave*32 .. +31
    const int lane = tid & 63;
    const int lam  = lane & 15;
    const int quad = lane >> 4;

    int rsel[4];
#pragma unroll
    for (int k = 0; k < 4; ++k) rsel[k] = idxp[o * 4 + k];

    // ---- one-time B panel stage: Bpan[e][k] = bf16(W[k-global][e0+e]) ----
    // thread -> (e = tid&31, k-chunk = (tid>>5)*16): 16 k-strided scalar
    // loads (coalesced over e: 32 consecutive floats/row), 2 ds_write_b128.
    {
        const int e  = tid & 31;
        const int k0 = (tid >> 5) * 16;
        float v[16];
#pragma unroll
        for (int j = 0; j < 16; ++j) {
            const int k = k0 + j;
            v[j] = W[(((o * 4 + (k >> 7)) * 128) + (k & 127)) * 128 + e0 + e];
        }
        bf16x8 w0, w1;
#pragma unroll
        for (int j = 0; j < 8; ++j) {
            w0[j] = (__bf16)v[j];
            w1[j] = (__bf16)v[8 + j];
        }
        *(bf16x8*)&Bpan[e * LDSB + k0]     = w0;
        *(bf16x8*)&Bpan[e * LDSB + k0 + 8] = w1;
    }

    const f32x4 zero4 = {0.f, 0.f, 0.f, 0.f};
    f32x4 acc[2][2];
#pragma unroll
    for (int mi = 0; mi < 2; ++mi)
#pragma unroll
        for (int ni = 0; ni < 2; ++ni) acc[mi][ni] = zero4;

    // A: per-lane row bases for the two fragments (rows wave*32+lam, +16)
    const float* xrow0 = x + (wave * 32 + lam)      * XROW;
    const float* xrow1 = x + (wave * 32 + 16 + lam) * XROW;

    // depth-2 A register prefetch stages (named, statically indexed)
    f32x4 sa0[4], sa1[4];

    auto loadA = [&](f32x4 (&SA)[4], const int kkc) {
        const int r  = rsel[kkc >> 2];
        const int dd = (kkc & 3) * 32 + quad * 8;
        const float* p0 = xrow0 + r * 128 + dd;
        const float* p1 = xrow1 + r * 128 + dd;
        SA[0] = *(const f32x4*)(p0);
        SA[1] = *(const f32x4*)(p0 + 4);
        SA[2] = *(const f32x4*)(p1);
        SA[3] = *(const f32x4*)(p1 + 4);
    };
    auto cvtA = [&](const f32x4 (&SA)[4], bf16x8 (&af)[2]) {
#pragma unroll
        for (int j = 0; j < 4; ++j) {
            af[0][j]     = (__bf16)SA[0][j];
            af[0][j + 4] = (__bf16)SA[1][j];
            af[1][j]     = (__bf16)SA[2][j];
            af[1][j + 4] = (__bf16)SA[3][j];
        }
    };

    loadA(sa0, 0);
    loadA(sa1, 1);
    __syncthreads();            // B panel visible; ONLY barrier before epilogue

    // ---- barrier-free K-loop: 16 steps of 32 k ----
#pragma unroll
    for (int kk = 0; kk < 16; ++kk) {
        bf16x8 af[2];
        if ((kk & 1) == 0) {
            cvtA(sa0, af);                        // consumes A(kk); stage free
            if (kk + 2 < 16) loadA(sa0, kk + 2);  // refill for kk+2
        } else {
            cvtA(sa1, af);
            if (kk + 2 < 16) loadA(sa1, kk + 2);
        }
        // B fragments from read-only LDS (balanced banks, no sync needed)
        const bf16x8 b0 = *(const bf16x8*)&Bpan[lam        * LDSB + kk * 32 + quad * 8];
        const bf16x8 b1 = *(const bf16x8*)&Bpan[(16 + lam) * LDSB + kk * 32 + quad * 8];
        acc[0][0] = __builtin_amdgcn_mfma_f32_16x16x32_bf16(af[0], b0, acc[0][0], 0, 0, 0);
        acc[0][1] = __builtin_amdgcn_mfma_f32_16x16x32_bf16(af[0], b1, acc[0][1], 0, 0, 0);
        acc[1][0] = __builtin_amdgcn_mfma_f32_16x16x32_bf16(af[1], b0, acc[1][0], 0, 0, 0);
        acc[1][1] = __builtin_amdgcn_mfma_f32_16x16x32_bf16(af[1], b1, acc[1][1], 0, 0, 0);
    }

    // ---- bias ----
    float bvals[2];
#pragma unroll
    for (int ni = 0; ni < 2; ++ni)
        bvals[ni] = bias[o * 128 + e0 + ni * 16 + lam];
#pragma unroll
    for (int mi = 0; mi < 2; ++mi)
#pragma unroll
        for (int ni = 0; ni < 2; ++ni)
#pragma unroll
            for (int rr = 0; rr < 4; ++rr) acc[mi][ni][rr] += bvals[ni];

    // ---- BN stats: block-local (block owns all 512 rows of its 32 cols) ----
#pragma unroll
    for (int ni = 0; ni < 2; ++ni) {
        float s = 0.f, q = 0.f;
#pragma unroll
        for (int mi = 0; mi < 2; ++mi)
#pragma unroll
            for (int rr = 0; rr < 4; ++rr) {
                const float v = acc[mi][ni][rr];
                s += v; q += v * v;
            }
        s += __shfl_xor(s, 16); s += __shfl_xor(s, 32);
        q += __shfl_xor(q, 16); q += __shfl_xor(q, 32);
        if (quad == 0) {
            Sred[wave][ni * 16 + lam] = s;
            Qred[wave][ni * 16 + lam] = q;
        }
    }
    __syncthreads();

    if (tid < 32) {
        float s = 0.f, q = 0.f;
#pragma unroll
        for (int w = 0; w < 16; ++w) {
            s += Sred[w][tid];
            q += Qred[w][tid];
        }
        const float mean = s * (1.0f / 512.0f);
        const float var  = q * (1.0f / 512.0f) - mean * mean;
        const float rstd = rsqrtf(var + 1e-5f);
        const float sc   = rstd * gamma[o * 128 + e0 + tid];
        sscale[tid] = sc;
        sshift[tid] = beta[o * 128 + e0 + tid] - mean * sc;
    }
    __syncthreads();

    // ---- normalize + SiLU in-register, store fp32 ----
#pragma unroll
    for (int mi = 0; mi < 2; ++mi) {
        const int rowb = wave * 32 + mi * 16 + quad * 4;
#pragma unroll
        for (int ni = 0; ni < 2; ++ni) {
            const int col = ni * 16 + lam;
            const float sc = sscale[col];
            const float sh = sshift[col];
#pragma unroll
            for (int rr = 0; rr < 4; ++rr) {
                const float xn = acc[mi][ni][rr] * sc + sh;
                const float sg = 1.0f / (1.0f + __expf(-xn));
                out[(rowb + rr) * FEAT + o * 128 + e0 + col] = xn * sg;
            }
        }
    }
}

extern "C" void kernel_launch(void* const* d_in, const int* in_sizes, int n_in,
                              void* d_out, int out_size, void* d_ws, size_t ws_size,
                              hipStream_t stream)
{
    const float* x     = (const float*)d_in[0];
    const float* W     = (const float*)d_in[1];
    const float* bias  = (const float*)d_in[2];
    const float* gamma = (const float*)d_in[3];
    const float* beta  = (const float*)d_in[4];
    const int*   idx   = (const int*)d_in[5];
    float* out = (float*)d_out;

    fused_encoder<<<dim3(256), dim3(1024), 0, stream>>>(
        x, W, bias, gamma, beta, idx, out);
}

// Round 8
// 110.018 us; speedup vs baseline: 1.0504x; 1.0504x over previous
//
#include <hip/hip_runtime.h>

// EncoderBlock, two-stage, BN block-local, barrier-free K-loop, BF16 PREP:
//  K0 (prep): x (16MB fp32) -> xb (8MB bf16), W (16MB) -> wb (8MB bf16) in ws.
//  K1 (fused): gather(xb, idx) -> GEMM slice (M=512 x N=32 @ K=512) + bias
//              -> block-local BN over 512 rows -> SiLU -> fp32 out.
// Why: R3/R6/R7 all streamed the gathered A panel as fp32 (8MB/XCD concurrent
// working set > 4MB L2 -> thrash, 256MB served by L3). bf16 panels make the
// per-XCD working set 4MB = L2-resident, give 100%-line A loads (16B = full
// k-fragment), and delete the 4.2M in-loop fp32->bf16 cvts.
// K1: 256 blocks=(o, 32-col slice) x 1024 thr (16 waves, 4/SIMD). A direct-to-
// register (depth-2 prefetch), B panel (32KB bf16) staged to LDS once, K-loop
// has NO barriers. No cross-block sync anywhere (R2/R4/R5: 50-80us cost).

typedef __attribute__((ext_vector_type(8))) __bf16 bf16x8;
typedef __attribute__((ext_vector_type(4))) float  f32x4;

#define FEAT 8192
#define XROW 8192            // N_IN * D_IN elems per batch row of x
#define LDSB 520             // B panel e-row stride in bf16 (512 + 8 pad)
#define NX8  524288          // x chunks of 8 floats (512*64*128/8)
#define NW8  524288          // W chunks of 8 floats (64*4*128*128/8)

__global__ __launch_bounds__(256)
void cvt_kernel(const float* __restrict__ x, const float* __restrict__ W,
                __bf16* __restrict__ xb, __bf16* __restrict__ wb)
{
    const int stride = gridDim.x * blockDim.x;
    for (int i = blockIdx.x * blockDim.x + threadIdx.x; i < NX8 + NW8; i += stride) {
        const float* src;
        __bf16* dst;
        int c;
        if (i < NX8) { src = x; dst = xb; c = i; }
        else         { src = W; dst = wb; c = i - NX8; }
        const f32x4 v0 = *(const f32x4*)(src + c * 8);
        const f32x4 v1 = *(const f32x4*)(src + c * 8 + 4);
        bf16x8 o;
#pragma unroll
        for (int j = 0; j < 4; ++j) {
            o[j]     = (__bf16)v0[j];
            o[j + 4] = (__bf16)v1[j];
        }
        *(bf16x8*)(dst + c * 8) = o;
    }
}

__global__ __launch_bounds__(1024, 4)
void fused_encoder(const __bf16* __restrict__ xb, const __bf16* __restrict__ wb,
                   const float* __restrict__ bias, const float* __restrict__ gamma,
                   const float* __restrict__ beta, const int* __restrict__ idxp,
                   float* __restrict__ out)
{
    __shared__ __bf16 Bpan[32 * LDSB];   // 32.5 KiB: B^T panel [e][k]
    __shared__ float Sred[16][32];
    __shared__ float Qred[16][32];
    __shared__ float sscale[32];
    __shared__ float sshift[32];

    // XCD-aware decode: 4 col-slices of one o share an XCD -> the o's 512KB
    // bf16 A panel is read once from HBM, 3x more from XCD-local L2.
    const int bid = blockIdx.x;
    const int o   = ((bid >> 5) << 3) | (bid & 7);
    const int es  = (bid >> 3) & 3;
    const int e0  = es * 32;

    const int tid  = threadIdx.x;
    const int wave = tid >> 6;          // 0..15 -> rows wave*32 .. +31
    const int lane = tid & 63;
    const int lam  = lane & 15;
    const int quad = lane >> 4;

    int rsel[4];
#pragma unroll
    for (int k = 0; k < 4; ++k) rsel[k] = idxp[o * 4 + k];

    // ---- one-time B panel stage: Bpan[e][k] = wb[k-global][e0+e] ----
    {
        const int e  = tid & 31;
        const int k0 = (tid >> 5) * 16;
        bf16x8 w0, w1;
#pragma unroll
        for (int j = 0; j < 8; ++j) {
            const int ka = k0 + j, kb = k0 + 8 + j;
            w0[j] = wb[(((o * 4 + (ka >> 7)) * 128) + (ka & 127)) * 128 + e0 + e];
            w1[j] = wb[(((o * 4 + (kb >> 7)) * 128) + (kb & 127)) * 128 + e0 + e];
        }
        *(bf16x8*)&Bpan[e * LDSB + k0]     = w0;
        *(bf16x8*)&Bpan[e * LDSB + k0 + 8] = w1;
    }

    const f32x4 zero4 = {0.f, 0.f, 0.f, 0.f};
    f32x4 acc[2][2];
#pragma unroll
    for (int mi = 0; mi < 2; ++mi)
#pragma unroll
        for (int ni = 0; ni < 2; ++ni) acc[mi][ni] = zero4;

    // A: per-lane row bases (rows wave*32+lam, +16); one bf16x8 load = the
    // lane's FULL k-fragment (16B, full-line-efficient).
    const __bf16* xrow0 = xb + (wave * 32 + lam)      * XROW;
    const __bf16* xrow1 = xb + (wave * 32 + 16 + lam) * XROW;

    // depth-2 A register prefetch (named stages, statically indexed)
    bf16x8 a0f0, a0f1, a1f0, a1f1;

    auto loadA = [&](bf16x8& F0, bf16x8& F1, const int kkc) {
        const int r  = rsel[kkc >> 2];
        const int dd = (kkc & 3) * 32 + quad * 8;
        F0 = *(const bf16x8*)(xrow0 + r * 128 + dd);
        F1 = *(const bf16x8*)(xrow1 + r * 128 + dd);
    };

    loadA(a0f0, a0f1, 0);
    loadA(a1f0, a1f1, 1);
    __syncthreads();            // B panel visible; only barrier before epilogue

    // ---- barrier-free K-loop: 16 steps of 32 k ----
#pragma unroll
    for (int kk = 0; kk < 16; ++kk) {
        const bf16x8 b0 = *(const bf16x8*)&Bpan[lam        * LDSB + kk * 32 + quad * 8];
        const bf16x8 b1 = *(const bf16x8*)&Bpan[(16 + lam) * LDSB + kk * 32 + quad * 8];
        if ((kk & 1) == 0) {
            acc[0][0] = __builtin_amdgcn_mfma_f32_16x16x32_bf16(a0f0, b0, acc[0][0], 0, 0, 0);
            acc[0][1] = __builtin_amdgcn_mfma_f32_16x16x32_bf16(a0f0, b1, acc[0][1], 0, 0, 0);
            acc[1][0] = __builtin_amdgcn_mfma_f32_16x16x32_bf16(a0f1, b0, acc[1][0], 0, 0, 0);
            acc[1][1] = __builtin_amdgcn_mfma_f32_16x16x32_bf16(a0f1, b1, acc[1][1], 0, 0, 0);
            if (kk + 2 < 16) loadA(a0f0, a0f1, kk + 2);   // refill stage 0
        } else {
            acc[0][0] = __builtin_amdgcn_mfma_f32_16x16x32_bf16(a1f0, b0, acc[0][0], 0, 0, 0);
            acc[0][1] = __builtin_amdgcn_mfma_f32_16x16x32_bf16(a1f0, b1, acc[0][1], 0, 0, 0);
            acc[1][0] = __builtin_amdgcn_mfma_f32_16x16x32_bf16(a1f1, b0, acc[1][0], 0, 0, 0);
            acc[1][1] = __builtin_amdgcn_mfma_f32_16x16x32_bf16(a1f1, b1, acc[1][1], 0, 0, 0);
            if (kk + 2 < 16) loadA(a1f0, a1f1, kk + 2);   // refill stage 1
        }
    }

    // ---- bias ----
    float bvals[2];
#pragma unroll
    for (int ni = 0; ni < 2; ++ni)
        bvals[ni] = bias[o * 128 + e0 + ni * 16 + lam];
#pragma unroll
    for (int mi = 0; mi < 2; ++mi)
#pragma unroll
        for (int ni = 0; ni < 2; ++ni)
#pragma unroll
            for (int rr = 0; rr < 4; ++rr) acc[mi][ni][rr] += bvals[ni];

    // ---- BN stats: block-local (block owns all 512 rows of its 32 cols) ----
#pragma unroll
    for (int ni = 0; ni < 2; ++ni) {
        float s = 0.f, q = 0.f;
#pragma unroll
        for (int mi = 0; mi < 2; ++mi)
#pragma unroll
            for (int rr = 0; rr < 4; ++rr) {
                const float v = acc[mi][ni][rr];
                s += v; q += v * v;
            }
        s += __shfl_xor(s, 16); s += __shfl_xor(s, 32);
        q += __shfl_xor(q, 16); q += __shfl_xor(q, 32);
        if (quad == 0) {
            Sred[wave][ni * 16 + lam] = s;
            Qred[wave][ni * 16 + lam] = q;
        }
    }
    __syncthreads();

    if (tid < 32) {
        float s = 0.f, q = 0.f;
#pragma unroll
        for (int w = 0; w < 16; ++w) {
            s += Sred[w][tid];
            q += Qred[w][tid];
        }
        const float mean = s * (1.0f / 512.0f);
        const float var  = q * (1.0f / 512.0f) - mean * mean;
        const float rstd = rsqrtf(var + 1e-5f);
        const float sc   = rstd * gamma[o * 128 + e0 + tid];
        sscale[tid] = sc;
        sshift[tid] = beta[o * 128 + e0 + tid] - mean * sc;
    }
    __syncthreads();

    // ---- normalize + SiLU in-register, store fp32 ----
#pragma unroll
    for (int mi = 0; mi < 2; ++mi) {
        const int rowb = wave * 32 + mi * 16 + quad * 4;
#pragma unroll
        for (int ni = 0; ni < 2; ++ni) {
            const int col = ni * 16 + lam;
            const float sc = sscale[col];
            const float sh = sshift[col];
#pragma unroll
            for (int rr = 0; rr < 4; ++rr) {
                const float xn = acc[mi][ni][rr] * sc + sh;
                const float sg = 1.0f / (1.0f + __expf(-xn));
                out[(rowb + rr) * FEAT + o * 128 + e0 + col] = xn * sg;
            }
        }
    }
}

extern "C" void kernel_launch(void* const* d_in, const int* in_sizes, int n_in,
                              void* d_out, int out_size, void* d_ws, size_t ws_size,
                              hipStream_t stream)
{
    const float* x     = (const float*)d_in[0];
    const float* W     = (const float*)d_in[1];
    const float* bias  = (const float*)d_in[2];
    const float* gamma = (const float*)d_in[3];
    const float* beta  = (const float*)d_in[4];
    const int*   idx   = (const int*)d_in[5];
    float* out = (float*)d_out;

    __bf16* xb = (__bf16*)d_ws;              // 8 MiB
    __bf16* wbp = xb + (size_t)NX8 * 8;      // 8 MiB

    cvt_kernel<<<dim3(1024), dim3(256), 0, stream>>>(x, W, xb, wbp);
    fused_encoder<<<dim3(256), dim3(1024), 0, stream>>>(
        xb, wbp, bias, gamma, beta, idx, out);
}

// Round 9
// 106.246 us; speedup vs baseline: 1.0877x; 1.0355x over previous
//
#include <hip/hip_runtime.h>

// EncoderBlock, two-stage, BN block-local, barrier-free K-loop, DEEP PREFETCH:
//  K0 (prep): x (16MB fp32) -> xb (8MB bf16) in ws.   (~4us)
//  K1 (fused): gather(xb, idx) -> GEMM slice (M=512 x N=32 @ K=512) + bias
//              -> block-local BN over 512 rows -> SiLU -> fp32 out.
// R3..R8 postmortem: GEMM stuck at 35-50us in EVERY structure with all pipes
// <10% busy and FETCH at the compulsory minimum => load-latency bound with
// too little memory-level parallelism (depth-2 = ~440cyc window < L3/HBM
// latency). Fix: depth-6 A register prefetch (12 outstanding VMEM instrs per
// wave, ~1300cyc window > HBM latency) + depth-2 register double-buffer for
// B LDS fragments. W is staged fp32->bf16 once in the prologue (x-only cvt).
// K1: 256 blocks=(o, 32-col slice) x 1024 thr (16 waves, 4/SIMD); no K-loop
// barriers; no cross-block sync anywhere (R2/R4/R5: 50-80us cost).

typedef __attribute__((ext_vector_type(8))) __bf16 bf16x8;
typedef __attribute__((ext_vector_type(4))) float  f32x4;

#define FEAT 8192
#define XROW 8192            // N_IN * D_IN elems per batch row of x
#define LDSB 520             // B panel e-row stride in bf16 (512 + 8 pad)
#define NX8  524288          // x chunks of 8 floats (512*64*128/8)
#define ADEPTH 6             // A prefetch depth (register stages)

__global__ __launch_bounds__(256)
void cvt_kernel(const float* __restrict__ x, __bf16* __restrict__ xb)
{
    const int stride = gridDim.x * blockDim.x;
    for (int c = blockIdx.x * blockDim.x + threadIdx.x; c < NX8; c += stride) {
        const f32x4 v0 = *(const f32x4*)(x + c * 8);
        const f32x4 v1 = *(const f32x4*)(x + c * 8 + 4);
        bf16x8 o;
#pragma unroll
        for (int j = 0; j < 4; ++j) {
            o[j]     = (__bf16)v0[j];
            o[j + 4] = (__bf16)v1[j];
        }
        *(bf16x8*)(xb + c * 8) = o;
    }
}

__global__ __launch_bounds__(1024, 4)
void fused_encoder(const __bf16* __restrict__ xb, const float* __restrict__ W,
                   const float* __restrict__ bias, const float* __restrict__ gamma,
                   const float* __restrict__ beta, const int* __restrict__ idxp,
                   float* __restrict__ out)
{
    __shared__ __bf16 Bpan[32 * LDSB];   // 32.5 KiB: B^T panel [e][k]
    __shared__ float Sred[16][32];
    __shared__ float Qred[16][32];
    __shared__ float sscale[32];
    __shared__ float sshift[32];

    // XCD-aware decode: 4 col-slices of one o share an XCD (A panel L2 reuse)
    const int bid = blockIdx.x;
    const int o   = ((bid >> 5) << 3) | (bid & 7);
    const int es  = (bid >> 3) & 3;
    const int e0  = es * 32;

    const int tid  = threadIdx.x;
    const int wave = tid >> 6;          // 0..15 -> rows wave*32 .. +31
    const int lane = tid & 63;
    const int lam  = lane & 15;
    const int quad = lane >> 4;

    int rsel[4];
#pragma unroll
    for (int k = 0; k < 4; ++k) rsel[k] = idxp[o * 4 + k];

    // A: per-lane row bases (rows wave*32+lam, +16); one bf16x8 = full k-frag
    const __bf16* xrow0 = xb + (wave * 32 + lam)      * XROW;
    const __bf16* xrow1 = xb + (wave * 32 + 16 + lam) * XROW;

    // depth-6 A register prefetch ring (indices static under full unroll)
    bf16x8 sa[ADEPTH][2];

    auto loadA = [&](const int stg, const int kkc) {
        const int r  = rsel[kkc >> 2];
        const int dd = (kkc & 3) * 32 + quad * 8;
        sa[stg][0] = *(const bf16x8*)(xrow0 + r * 128 + dd);
        sa[stg][1] = *(const bf16x8*)(xrow1 + r * 128 + dd);
    };

    // issue the first ADEPTH steps' A loads NOW (they fly during B staging)
#pragma unroll
    for (int p = 0; p < ADEPTH; ++p) loadA(p, p);

    // ---- one-time B panel stage: Bpan[e][k] = bf16(W[k-global][e0+e]) ----
    {
        const int e  = tid & 31;
        const int k0 = (tid >> 5) * 16;
        float v[16];
#pragma unroll
        for (int j = 0; j < 16; ++j) {
            const int k = k0 + j;
            v[j] = W[(((o * 4 + (k >> 7)) * 128) + (k & 127)) * 128 + e0 + e];
        }
        bf16x8 w0, w1;
#pragma unroll
        for (int j = 0; j < 8; ++j) {
            w0[j] = (__bf16)v[j];
            w1[j] = (__bf16)v[8 + j];
        }
        *(bf16x8*)&Bpan[e * LDSB + k0]     = w0;
        *(bf16x8*)&Bpan[e * LDSB + k0 + 8] = w1;
    }

    const f32x4 zero4 = {0.f, 0.f, 0.f, 0.f};
    f32x4 acc[2][2];
#pragma unroll
    for (int mi = 0; mi < 2; ++mi)
#pragma unroll
        for (int ni = 0; ni < 2; ++ni) acc[mi][ni] = zero4;

    __syncthreads();            // B panel visible; only barrier before epilogue

    // B fragment double-buffer (depth-2, LDS latency hidden under MFMA)
    bf16x8 bq[2][2];
    bq[0][0] = *(const bf16x8*)&Bpan[lam        * LDSB + quad * 8];
    bq[0][1] = *(const bf16x8*)&Bpan[(16 + lam) * LDSB + quad * 8];

    // ---- barrier-free K-loop: 16 steps of 32 k ----
#pragma unroll
    for (int kk = 0; kk < 16; ++kk) {
        const int cur = kk & 1;
        const int stg = kk % ADEPTH;             // static under full unroll
        if (kk + 1 < 16) {                       // prefetch next B frags
            bq[cur ^ 1][0] = *(const bf16x8*)&Bpan[lam        * LDSB + (kk + 1) * 32 + quad * 8];
            bq[cur ^ 1][1] = *(const bf16x8*)&Bpan[(16 + lam) * LDSB + (kk + 1) * 32 + quad * 8];
        }
        // consume A stage stg + B cur (vmcnt/lgkm waits auto-inserted)
        acc[0][0] = __builtin_amdgcn_mfma_f32_16x16x32_bf16(sa[stg][0], bq[cur][0], acc[0][0], 0, 0, 0);
        acc[0][1] = __builtin_amdgcn_mfma_f32_16x16x32_bf16(sa[stg][0], bq[cur][1], acc[0][1], 0, 0, 0);
        acc[1][0] = __builtin_amdgcn_mfma_f32_16x16x32_bf16(sa[stg][1], bq[cur][0], acc[1][0], 0, 0, 0);
        acc[1][1] = __builtin_amdgcn_mfma_f32_16x16x32_bf16(sa[stg][1], bq[cur][1], acc[1][1], 0, 0, 0);
        if (kk + ADEPTH < 16) loadA(stg, kk + ADEPTH);   // refill freed stage
    }

    // ---- bias ----
    float bvals[2];
#pragma unroll
    for (int ni = 0; ni < 2; ++ni)
        bvals[ni] = bias[o * 128 + e0 + ni * 16 + lam];
#pragma unroll
    for (int mi = 0; mi < 2; ++mi)
#pragma unroll
        for (int ni = 0; ni < 2; ++ni)
#pragma unroll
            for (int rr = 0; rr < 4; ++rr) acc[mi][ni][rr] += bvals[ni];

    // ---- BN stats: block-local (block owns all 512 rows of its 32 cols) ----
#pragma unroll
    for (int ni = 0; ni < 2; ++ni) {
        float s = 0.f, q = 0.f;
#pragma unroll
        for (int mi = 0; mi < 2; ++mi)
#pragma unroll
            for (int rr = 0; rr < 4; ++rr) {
                const float v = acc[mi][ni][rr];
                s += v; q += v * v;
            }
        s += __shfl_xor(s, 16); s += __shfl_xor(s, 32);
        q += __shfl_xor(q, 16); q += __shfl_xor(q, 32);
        if (quad == 0) {
            Sred[wave][ni * 16 + lam] = s;
            Qred[wave][ni * 16 + lam] = q;
        }
    }
    __syncthreads();

    if (tid < 32) {
        float s = 0.f, q = 0.f;
#pragma unroll
        for (int w = 0; w < 16; ++w) {
            s += Sred[w][tid];
            q += Qred[w][tid];
        }
        const float mean = s * (1.0f / 512.0f);
        const float var  = q * (1.0f / 512.0f) - mean * mean;
        const float rstd = rsqrtf(var + 1e-5f);
        const float sc   = rstd * gamma[o * 128 + e0 + tid];
        sscale[tid] = sc;
        sshift[tid] = beta[o * 128 + e0 + tid] - mean * sc;
    }
    __syncthreads();

    // ---- normalize + SiLU in-register, store fp32 ----
#pragma unroll
    for (int mi = 0; mi < 2; ++mi) {
        const int rowb = wave * 32 + mi * 16 + quad * 4;
#pragma unroll
        for (int ni = 0; ni < 2; ++ni) {
            const int col = ni * 16 + lam;
            const float sc = sscale[col];
            const float sh = sshift[col];
#pragma unroll
            for (int rr = 0; rr < 4; ++rr) {
                const float xn = acc[mi][ni][rr] * sc + sh;
                const float sg = 1.0f / (1.0f + __expf(-xn));
                out[(rowb + rr) * FEAT + o * 128 + e0 + col] = xn * sg;
            }
        }
    }
}

extern "C" void kernel_launch(void* const* d_in, const int* in_sizes, int n_in,
                              void* d_out, int out_size, void* d_ws, size_t ws_size,
                              hipStream_t stream)
{
    const float* x     = (const float*)d_in[0];
    const float* W     = (const float*)d_in[1];
    const float* bias  = (const float*)d_in[2];
    const float* gamma = (const float*)d_in[3];
    const float* beta  = (const float*)d_in[4];
    const int*   idx   = (const int*)d_in[5];
    float* out = (float*)d_out;

    __bf16* xb = (__bf16*)d_ws;              // 8 MiB

    cvt_kernel<<<dim3(512), dim3(256), 0, stream>>>(x, xb);
    fused_encoder<<<dim3(256), dim3(1024), 0, stream>>>(
        xb, W, bias, gamma, beta, idx, out);
}

// Round 10
// 105.850 us; speedup vs baseline: 1.0917x; 1.0037x over previous
//
#include <hip/hip_runtime.h>

// EncoderBlock, two-stage, BN block-local, barrier-free K-loop, CHANNEL-DECAMPED:
//  K0 (prep): x (16MB fp32) -> xb bf16 with SKEWED batch stride (8320 elems =
//             16640B, mod 4096 = 256) so consecutive batches land on different
//             L2/L3 channel-select slots.
//  K1 (fused): gather(xb) -> GEMM slice (M=512 x N=32 @ K=512) + bias ->
//              block-local BN over 512 rows -> SiLU -> fp32 out.
// R3..R9 postmortem: GEMM stuck at 33-50us in EVERY structure, pipes <10%
// busy, MLP depth didn't matter => memory-channel camping: A reads at 16/32KB
// power-of-2 stride put the whole grid's per-phase traffic on a few channels
// (addr bits [11:8] independent of batch). Fix #1: skewed xb stride. Fix #2:
// per-wave K-phase rotation (wave w starts at step w; accumulation is
// order-independent) so one block's 16 waves hit 16 distinct (r,dd) windows.
// K1: 256 blocks=(o, 32-col slice) x 1024 thr (16 waves, 4/SIMD); A direct-to-
// register depth-6 prefetch ring; B panel (32KB bf16) in LDS once; no K-loop
// barriers; no cross-block sync (R2/R4/R5: 50-80us cost).

typedef __attribute__((ext_vector_type(8))) __bf16 bf16x8;
typedef __attribute__((ext_vector_type(4))) float  f32x4;

#define FEAT 8192
#define XROWP 8320           // skewed xb batch stride in elems (16640B)
#define LDSB 520             // B panel e-row stride in bf16 (512 + 8 pad)
#define NX8  524288          // x chunks of 8 floats (512*64*128/8)
#define ADEPTH 6             // A prefetch depth (register stages)

__global__ __launch_bounds__(256)
void cvt_kernel(const float* __restrict__ x, __bf16* __restrict__ xb)
{
    const int stride = gridDim.x * blockDim.x;
    for (int c = blockIdx.x * blockDim.x + threadIdx.x; c < NX8; c += stride) {
        const int b = c >> 10;          // 1024 8-elem chunks per batch row
        const int j = c & 1023;
        const f32x4 v0 = *(const f32x4*)(x + c * 8);
        const f32x4 v1 = *(const f32x4*)(x + c * 8 + 4);
        bf16x8 o;
#pragma unroll
        for (int jj = 0; jj < 4; ++jj) {
            o[jj]     = (__bf16)v0[jj];
            o[jj + 4] = (__bf16)v1[jj];
        }
        *(bf16x8*)(xb + (size_t)b * XROWP + j * 8) = o;
    }
}

__global__ __launch_bounds__(1024, 4)
void fused_encoder(const __bf16* __restrict__ xb, const float* __restrict__ W,
                   const float* __restrict__ bias, const float* __restrict__ gamma,
                   const float* __restrict__ beta, const int* __restrict__ idxp,
                   float* __restrict__ out)
{
    __shared__ __bf16 Bpan[32 * LDSB];   // 32.5 KiB: B^T panel [e][k]
    __shared__ float Sred[16][32];
    __shared__ float Qred[16][32];
    __shared__ float sscale[32];
    __shared__ float sshift[32];

    // XCD-aware decode: 4 col-slices of one o share an XCD (A panel L2 reuse)
    const int bid = blockIdx.x;
    const int o   = ((bid >> 5) << 3) | (bid & 7);
    const int es  = (bid >> 3) & 3;
    const int e0  = es * 32;

    const int tid  = threadIdx.x;
    const int wave = tid >> 6;          // 0..15 -> rows wave*32 .. +31
    const int lane = tid & 63;
    const int lam  = lane & 15;
    const int quad = lane >> 4;

    // gathered row ids as 4 NAMED scalars (runtime kidx -> branchless select,
    // no runtime-indexed array => no scratch)
    const int r0 = idxp[o * 4 + 0];
    const int r1 = idxp[o * 4 + 1];
    const int r2 = idxp[o * 4 + 2];
    const int r3 = idxp[o * 4 + 3];

    // A: per-lane row bases (rows wave*32+lam, +16); one bf16x8 = full k-frag
    const __bf16* xrow0 = xb + (size_t)(wave * 32 + lam)      * XROWP;
    const __bf16* xrow1 = xb + (size_t)(wave * 32 + 16 + lam) * XROWP;

    auto rowOf = [&](const int kc) -> int {
        const int kidx = kc >> 2;
        const int ra = (kidx & 1) ? r1 : r0;
        const int rb = (kidx & 1) ? r3 : r2;
        return (kidx & 2) ? rb : ra;
    };

    // depth-6 A register prefetch ring (stage indices static under unroll)
    bf16x8 sa[ADEPTH][2];
    auto loadA = [&](bf16x8& F0, bf16x8& F1, const int kc) {
        const int r  = rowOf(kc);
        const int dd = (kc & 3) * 32 + quad * 8;
        F0 = *(const bf16x8*)(xrow0 + r * 128 + dd);
        F1 = *(const bf16x8*)(xrow1 + r * 128 + dd);
    };

    // per-wave K-phase rotation: wave w starts at step w (order-independent)
    const int kk0 = wave;

    // issue the first ADEPTH rotated steps' A loads NOW (fly during B staging)
#pragma unroll
    for (int p = 0; p < ADEPTH; ++p)
        loadA(sa[p][0], sa[p][1], (kk0 + p) & 15);

    // ---- one-time B panel stage: Bpan[e][k] = bf16(W[k-global][e0+e]) ----
    {
        const int e  = tid & 31;
        const int k0 = (tid >> 5) * 16;
        float v[16];
#pragma unroll
        for (int j = 0; j < 16; ++j) {
            const int k = k0 + j;
            v[j] = W[(((o * 4 + (k >> 7)) * 128) + (k & 127)) * 128 + e0 + e];
        }
        bf16x8 w0, w1;
#pragma unroll
        for (int j = 0; j < 8; ++j) {
            w0[j] = (__bf16)v[j];
            w1[j] = (__bf16)v[8 + j];
        }
        *(bf16x8*)&Bpan[e * LDSB + k0]     = w0;
        *(bf16x8*)&Bpan[e * LDSB + k0 + 8] = w1;
    }

    const f32x4 zero4 = {0.f, 0.f, 0.f, 0.f};
    f32x4 acc[2][2];
#pragma unroll
    for (int mi = 0; mi < 2; ++mi)
#pragma unroll
        for (int ni = 0; ni < 2; ++ni) acc[mi][ni] = zero4;

    __syncthreads();            // B panel visible; only barrier before epilogue

    // B fragment double-buffer (depth-2, LDS latency hidden under MFMA)
    bf16x8 bq[2][2];
    bq[0][0] = *(const bf16x8*)&Bpan[lam        * LDSB + kk0 * 32 + quad * 8];
    bq[0][1] = *(const bf16x8*)&Bpan[(16 + lam) * LDSB + kk0 * 32 + quad * 8];

    // ---- barrier-free rotated K-loop: 16 steps of 32 k ----
#pragma unroll
    for (int i = 0; i < 16; ++i) {
        const int cur = i & 1;              // static under unroll
        const int stg = i % ADEPTH;         // static under unroll
        if (i + 1 < 16) {                   // prefetch next B frags (runtime kn)
            const int kn = (kk0 + i + 1) & 15;
            bq[cur ^ 1][0] = *(const bf16x8*)&Bpan[lam        * LDSB + kn * 32 + quad * 8];
            bq[cur ^ 1][1] = *(const bf16x8*)&Bpan[(16 + lam) * LDSB + kn * 32 + quad * 8];
        }
        acc[0][0] = __builtin_amdgcn_mfma_f32_16x16x32_bf16(sa[stg][0], bq[cur][0], acc[0][0], 0, 0, 0);
        acc[0][1] = __builtin_amdgcn_mfma_f32_16x16x32_bf16(sa[stg][0], bq[cur][1], acc[0][1], 0, 0, 0);
        acc[1][0] = __builtin_amdgcn_mfma_f32_16x16x32_bf16(sa[stg][1], bq[cur][0], acc[1][0], 0, 0, 0);
        acc[1][1] = __builtin_amdgcn_mfma_f32_16x16x32_bf16(sa[stg][1], bq[cur][1], acc[1][1], 0, 0, 0);
        if (i + ADEPTH < 16)                // refill freed stage (rotated step)
            loadA(sa[stg][0], sa[stg][1], (kk0 + i + ADEPTH) & 15);
    }

    // ---- bias ----
    float bvals[2];
#pragma unroll
    for (int ni = 0; ni < 2; ++ni)
        bvals[ni] = bias[o * 128 + e0 + ni * 16 + lam];
#pragma unroll
    for (int mi = 0; mi < 2; ++mi)
#pragma unroll
        for (int ni = 0; ni < 2; ++ni)
#pragma unroll
            for (int rr = 0; rr < 4; ++rr) acc[mi][ni][rr] += bvals[ni];

    // ---- BN stats: block-local (block owns all 512 rows of its 32 cols) ----
#pragma unroll
    for (int ni = 0; ni < 2; ++ni) {
        float s = 0.f, q = 0.f;
#pragma unroll
        for (int mi = 0; mi < 2; ++mi)
#pragma unroll
            for (int rr = 0; rr < 4; ++rr) {
                const float v = acc[mi][ni][rr];
                s += v; q += v * v;
            }
        s += __shfl_xor(s, 16); s += __shfl_xor(s, 32);
        q += __shfl_xor(q, 16); q += __shfl_xor(q, 32);
        if (quad == 0) {
            Sred[wave][ni * 16 + lam] = s;
            Qred[wave][ni * 16 + lam] = q;
        }
    }
    __syncthreads();

    if (tid < 32) {
        float s = 0.f, q = 0.f;
#pragma unroll
        for (int w = 0; w < 16; ++w) {
            s += Sred[w][tid];
            q += Qred[w][tid];
        }
        const float mean = s * (1.0f / 512.0f);
        const float var  = q * (1.0f / 512.0f) - mean * mean;
        const float rstd = rsqrtf(var + 1e-5f);
        const float sc   = rstd * gamma[o * 128 + e0 + tid];
        sscale[tid] = sc;
        sshift[tid] = beta[o * 128 + e0 + tid] - mean * sc;
    }
    __syncthreads();

    // ---- normalize + SiLU in-register, store fp32 ----
#pragma unroll
    for (int mi = 0; mi < 2; ++mi) {
        const int rowb = wave * 32 + mi * 16 + quad * 4;
#pragma unroll
        for (int ni = 0; ni < 2; ++ni) {
            const int col = ni * 16 + lam;
            const float sc = sscale[col];
            const float sh = sshift[col];
#pragma unroll
            for (int rr = 0; rr < 4; ++rr) {
                const float xn = acc[mi][ni][rr] * sc + sh;
                const float sg = 1.0f / (1.0f + __expf(-xn));
                out[(rowb + rr) * FEAT + o * 128 + e0 + col] = xn * sg;
            }
        }
    }
}

extern "C" void kernel_launch(void* const* d_in, const int* in_sizes, int n_in,
                              void* d_out, int out_size, void* d_ws, size_t ws_size,
                              hipStream_t stream)
{
    const float* x     = (const float*)d_in[0];
    const float* W     = (const float*)d_in[1];
    const float* bias  = (const float*)d_in[2];
    const float* gamma = (const float*)d_in[3];
    const float* beta  = (const float*)d_in[4];
    const int*   idx   = (const int*)d_in[5];
    float* out = (float*)d_out;

    __bf16* xb = (__bf16*)d_ws;              // 512*8320*2B = 8.5 MiB

    cvt_kernel<<<dim3(512), dim3(256), 0, stream>>>(x, xb);
    fused_encoder<<<dim3(256), dim3(1024), 0, stream>>>(
        xb, W, bias, gamma, beta, idx, out);
}